// Round 1
// baseline (1902.117 us; speedup 1.0000x reference)
//
#include <hip/hip_runtime.h>
#include <stdint.h>

typedef __bf16 bf16_t;
typedef __bf16 bf16x8 __attribute__((ext_vector_type(8)));
typedef __bf16 bf16x4 __attribute__((ext_vector_type(4)));
typedef float f32x4 __attribute__((ext_vector_type(4)));
typedef unsigned short ushort_t;

#define CC 768
#define HD 3072
#define TB 196
#define HWD 14
#define EPSF 1e-5f
#define INV_T (1.0f/196.0f)

// ---------------- helpers ----------------
__device__ __forceinline__ float wave_sum(float v) {
#pragma unroll
  for (int off = 32; off > 0; off >>= 1) v += __shfl_xor(v, off, 64);
  return v;
}

// CK-style global->LDS async copy, 16B per lane. LDS dest must be
// wave-uniform base; HW scatters lane i at base + i*16B.
__device__ __forceinline__ void async_copy16(const void* g, void* l) {
  typedef __attribute__((address_space(3))) uint32_t lds_u32;
  typedef __attribute__((address_space(1))) const uint32_t glb_u32;
  glb_u32* gp = (glb_u32*)(uintptr_t)g;
  lds_u32* lp = (lds_u32*)(uint32_t)(uintptr_t)l;  // low 32 bits of generic LDS ptr == LDS offset
  __builtin_amdgcn_global_load_lds(gp, lp, 16, 0, 0);
}

// ---------------- LN0 (fused: write normalized row + stats of OUTPUT row) ----------------
__global__ __launch_bounds__(256) void k_ln0(const float* __restrict__ in,
                                             const float* __restrict__ g,
                                             const float* __restrict__ b,
                                             float* __restrict__ out,
                                             float* __restrict__ st, int M) {
  int row = blockIdx.x * 4 + (threadIdx.x >> 6);
  if (row >= M) return;
  int lane = threadIdx.x & 63;
  const float* rp = in + (size_t)row * CC;
  int c0 = lane * 4;
  f32x4 x[3];
#pragma unroll
  for (int s = 0; s < 3; ++s) x[s] = *(const f32x4*)(rp + s * 256 + c0);
  float sum = 0.f;
#pragma unroll
  for (int s = 0; s < 3; ++s)
#pragma unroll
    for (int j = 0; j < 4; ++j) sum += x[s][j];
  float mean = wave_sum(sum) * (1.0f / CC);
  float s2 = 0.f;
#pragma unroll
  for (int s = 0; s < 3; ++s)
#pragma unroll
    for (int j = 0; j < 4; ++j) { float d = x[s][j] - mean; s2 += d * d; }
  float rs = rsqrtf(wave_sum(s2) * (1.0f / CC) + EPSF);
  float* op = out + (size_t)row * CC;
  f32x4 o[3];
  float sum2 = 0.f;
#pragma unroll
  for (int s = 0; s < 3; ++s) {
    int cc = s * 256 + c0;
    f32x4 gg = *(const f32x4*)(g + cc);
    f32x4 bb = *(const f32x4*)(b + cc);
#pragma unroll
    for (int j = 0; j < 4; ++j) {
      o[s][j] = (x[s][j] - mean) * rs * gg[j] + bb[j];
      sum2 += o[s][j];
    }
    *(f32x4*)(op + cc) = o[s];
  }
  // stats of the normalized output (feeds LN1 inside mix)
  float mean2 = wave_sum(sum2) * (1.0f / CC);
  float q2 = 0.f;
#pragma unroll
  for (int s = 0; s < 3; ++s)
#pragma unroll
    for (int j = 0; j < 4; ++j) { float d = o[s][j] - mean2; q2 += d * d; }
  float rs2 = rsqrtf(wave_sum(q2) * (1.0f / CC) + EPSF);
  if (lane == 0) { st[2 * row] = mean2; st[2 * row + 1] = rs2; }
}

// ---------------- per-row mean/rstd ----------------
__global__ __launch_bounds__(256) void k_stats(const float* __restrict__ in,
                                               float* __restrict__ st, int M) {
  int row = blockIdx.x * 4 + (threadIdx.x >> 6);
  if (row >= M) return;
  int lane = threadIdx.x & 63;
  const float* rp = in + (size_t)row * CC;
  int c0 = lane * 4;
  f32x4 x[3];
#pragma unroll
  for (int s = 0; s < 3; ++s) x[s] = *(const f32x4*)(rp + s * 256 + c0);
  float sum = 0.f;
#pragma unroll
  for (int s = 0; s < 3; ++s)
#pragma unroll
    for (int j = 0; j < 4; ++j) sum += x[s][j];
  float mean = wave_sum(sum) * (1.0f / CC);
  float s2 = 0.f;
#pragma unroll
  for (int s = 0; s < 3; ++s)
#pragma unroll
    for (int j = 0; j < 4; ++j) { float d = x[s][j] - mean; s2 += d * d; }
  float rs = rsqrtf(wave_sum(s2) * (1.0f / CC) + EPSF);
  if (lane == 0) { st[2 * row] = mean; st[2 * row + 1] = rs; }
}

// ---------------- LN + q_shift + token-mix, bf16 outputs ----------------
// NOUT=3: xk,xv,xr (attention). NOUT=2: xk,xr (ffn).
template <int NOUT>
__global__ __launch_bounds__(256) void k_mix(const float* __restrict__ xb,
                                             const float* __restrict__ st,
                                             const float* __restrict__ g,
                                             const float* __restrict__ b,
                                             const float* __restrict__ mk,
                                             const float* __restrict__ mv,
                                             const float* __restrict__ mr,
                                             bf16_t* __restrict__ ok,
                                             bf16_t* __restrict__ ov,
                                             bf16_t* __restrict__ orr, int M) {
  int tok = blockIdx.x * 4 + (threadIdx.x >> 6);
  if (tok >= M) return;
  int lane = threadIdx.x & 63;
  int t = tok % TB;
  int h = t / HWD, w = t % HWD;
  int nbr[4];
  nbr[0] = (w > 0)       ? tok - 1   : -1;   // ch [0,192):   from left
  nbr[1] = (w < HWD - 1) ? tok + 1   : -1;   // ch [192,384): from right
  nbr[2] = (h > 0)       ? tok - HWD : -1;   // ch [384,576): from up
  nbr[3] = (h < HWD - 1) ? tok + HWD : -1;   // ch [576,768): from down
  float ms = st[2 * tok], rss = st[2 * tok + 1];
  const float* rp = xb + (size_t)tok * CC;
#pragma unroll
  for (int s = 0; s < 3; ++s) {
    int cc = s * 256 + lane * 4;
    int grp = cc / 192;
    int nb = nbr[grp];
    f32x4 xs = *(const f32x4*)(rp + cc);
    f32x4 xn = {0.f, 0.f, 0.f, 0.f};
    float mn = 0.f, rsn = 0.f;
    if (nb >= 0) {
      xn = *(const f32x4*)(xb + (size_t)nb * CC + cc);
      mn = st[2 * nb];
      rsn = st[2 * nb + 1];
    }
    f32x4 gg = *(const f32x4*)(g + cc);
    f32x4 bb = *(const f32x4*)(b + cc);
    f32x4 mk4 = *(const f32x4*)(mk + cc);
    f32x4 mr4 = *(const f32x4*)(mr + cc);
    f32x4 mv4 = {0.f, 0.f, 0.f, 0.f};
    if (NOUT == 3) mv4 = *(const f32x4*)(mv + cc);
    bf16x4 vk, vv, vr;
#pragma unroll
    for (int j = 0; j < 4; ++j) {
      float xi = (xs[j] - ms) * rss * gg[j] + bb[j];
      float xx = (nb >= 0) ? ((xn[j] - mn) * rsn * gg[j] + bb[j]) : 0.f;
      vk[j] = (bf16_t)(xi * mk4[j] + xx * (1.0f - mk4[j]));
      if (NOUT == 3) vv[j] = (bf16_t)(xi * mv4[j] + xx * (1.0f - mv4[j]));
      vr[j] = (bf16_t)(xi * mr4[j] + xx * (1.0f - mr4[j]));
    }
    *(bf16x4*)(ok + (size_t)tok * CC + cc) = vk;
    if (NOUT == 3) *(bf16x4*)(ov + (size_t)tok * CC + cc) = vv;
    *(bf16x4*)(orr + (size_t)tok * CC + cc) = vr;
  }
}

// ---------------- weight f32 (K,N) -> bf16 transposed (N,K) ----------------
__global__ __launch_bounds__(256) void k_tcvt(const float* __restrict__ src,
                                              bf16_t* __restrict__ dst, int K, int N) {
  __shared__ float tile[32][33];
  int tx = threadIdx.x & 31;
  int ty = threadIdx.x >> 5;
  int n0 = blockIdx.x * 32, k0 = blockIdx.y * 32;
#pragma unroll
  for (int i = 0; i < 4; ++i)
    tile[ty + 8 * i][tx] = src[(size_t)(k0 + ty + 8 * i) * N + n0 + tx];
  __syncthreads();
#pragma unroll
  for (int i = 0; i < 4; ++i)
    dst[(size_t)(n0 + ty + 8 * i) * K + k0 + tx] = (bf16_t)tile[tx][ty + 8 * i];
}

// ---------------- MFMA GEMM: C[M,N] = A[M,K](bf16) @ Bt[N,K](bf16)^T ----------------
enum { EPI_F32 = 0, EPI_SIG_BF16 = 1, EPI_RELU2 = 2, EPI_ADD = 3 };

template <int EPI>
__global__ __launch_bounds__(256) void k_gemm(const bf16_t* __restrict__ A,
                                              const bf16_t* __restrict__ Bt,
                                              void* __restrict__ Cout,
                                              int M, int N, int K) {
  __shared__ __align__(16) ushort_t As[128 * 32];
  __shared__ __align__(16) ushort_t Bs[128 * 32];
  int tid = threadIdx.x;
  int wave = tid >> 6, lane = tid & 63;
  int bm = blockIdx.y * 128, bn = blockIdx.x * 128;
  int srow = wave * 16 + (lane >> 2);
  int scol = (lane & 3) * 8;
  int wm = (wave >> 1) * 64, wn = (wave & 1) * 64;
  int fr = lane & 15, fq = lane >> 4;
  f32x4 acc[4][4] = {};
  for (int kt = 0; kt < K; kt += 32) {
#pragma unroll
    for (int i = 0; i < 2; ++i) {
      int arow = bm + i * 64 + srow;
      if (arow >= M) arow = M - 1;  // clamp (stores are guarded)
      async_copy16(A + (size_t)arow * K + kt + scol, As + (i * 64 + wave * 16) * 32);
      async_copy16(Bt + (size_t)(bn + i * 64 + srow) * K + kt + scol,
                   Bs + (i * 64 + wave * 16) * 32);
    }
    __syncthreads();  // drains vmcnt before barrier
    bf16x8 af[4], bfv[4];
#pragma unroll
    for (int i = 0; i < 4; ++i) {
      af[i]  = *(const bf16x8*)(As + (wm + i * 16 + fr) * 32 + fq * 8);
      bfv[i] = *(const bf16x8*)(Bs + (wn + i * 16 + fr) * 32 + fq * 8);
    }
#pragma unroll
    for (int mi = 0; mi < 4; ++mi)
#pragma unroll
      for (int ni = 0; ni < 4; ++ni)
        acc[mi][ni] = __builtin_amdgcn_mfma_f32_16x16x32_bf16(af[mi], bfv[ni], acc[mi][ni], 0, 0, 0);
    __syncthreads();
  }
#pragma unroll
  for (int mi = 0; mi < 4; ++mi) {
#pragma unroll
    for (int ni = 0; ni < 4; ++ni) {
#pragma unroll
      for (int r = 0; r < 4; ++r) {
        int grow = bm + wm + mi * 16 + fq * 4 + r;
        int gcol = bn + wn + ni * 16 + fr;
        if (grow < M) {
          size_t idx = (size_t)grow * N + gcol;
          float v = acc[mi][ni][r];
          if (EPI == EPI_F32) {
            ((float*)Cout)[idx] = v;
          } else if (EPI == EPI_RELU2) {
            float t = v > 0.f ? v : 0.f;
            ((float*)Cout)[idx] = t * t;
          } else if (EPI == EPI_SIG_BF16) {
            ((bf16_t*)Cout)[idx] = (bf16_t)(1.0f / (1.0f + __expf(-v)));
          } else {  // EPI_ADD: residual accumulate in place
            ((float*)Cout)[idx] += v;
          }
        }
      }
    }
  }
}

// ---------------- bidirectional WKV scans ----------------
// kmax subtraction omitted: num/den ratio is invariant and |k| is small.
__global__ __launch_bounds__(256) void k_wkv_bwd(const float* __restrict__ k,
                                                 const float* __restrict__ v,
                                                 const float* __restrict__ decay,
                                                 float* __restrict__ ba,
                                                 float* __restrict__ bb, int CB) {
  int idx = blockIdx.x * 256 + threadIdx.x;
  if (idx >= CB * CC) return;
  int c = idx % CC;
  size_t base = (size_t)(idx / CC) * TB * CC + c;
  float w = decay[c] * INV_T;
  float d = __expf(-w);
  float a = 0.f, bs = 0.f;
  for (int t = TB - 1; t >= 0; --t) {
    size_t p = base + (size_t)t * CC;
    ba[p] = a;
    bb[p] = bs;
    float ek = __expf(k[p]);
    a = d * (a + ek * v[p]);
    bs = d * (bs + ek);
  }
}

__global__ __launch_bounds__(256) void k_wkv_fwd(const float* __restrict__ k,
                                                 const float* __restrict__ v,
                                                 const float* __restrict__ decay,
                                                 const float* __restrict__ first,
                                                 const float* __restrict__ ba,
                                                 const float* __restrict__ bb,
                                                 float* __restrict__ r, int CB) {
  int idx = blockIdx.x * 256 + threadIdx.x;
  if (idx >= CB * CC) return;
  int c = idx % CC;
  size_t base = (size_t)(idx / CC) * TB * CC + c;
  float w = decay[c] * INV_T;
  float d = __expf(-w);
  float ew = __expf(w);
  float u = first[c] * INV_T;
  float a = 0.f, bs = 0.f;
  for (int t = 0; t < TB; ++t) {
    size_t p = base + (size_t)t * CC;
    float kk = k[p], vv = v[p];
    float eu = __expf(u + kk);
    float num = ew * (a + ba[p]) + eu * vv;
    float den = ew * (bs + bb[p]) + eu;
    r[p] = num / den;
    float ek = __expf(kk);
    a = d * (a + ek * vv);
    bs = d * (bs + ek);
  }
}

// ---------------- LN(rwkv) * sr -> bf16 ----------------
__global__ __launch_bounds__(256) void k_ln_mul(const float* __restrict__ in,
                                                const bf16_t* __restrict__ sr,
                                                const float* __restrict__ g,
                                                const float* __restrict__ b,
                                                bf16_t* __restrict__ out, int M) {
  int row = blockIdx.x * 4 + (threadIdx.x >> 6);
  if (row >= M) return;
  int lane = threadIdx.x & 63;
  const float* rp = in + (size_t)row * CC;
  int c0 = lane * 4;
  f32x4 x[3];
#pragma unroll
  for (int s = 0; s < 3; ++s) x[s] = *(const f32x4*)(rp + s * 256 + c0);
  float sum = 0.f;
#pragma unroll
  for (int s = 0; s < 3; ++s)
#pragma unroll
    for (int j = 0; j < 4; ++j) sum += x[s][j];
  float mean = wave_sum(sum) * (1.0f / CC);
  float s2 = 0.f;
#pragma unroll
  for (int s = 0; s < 3; ++s)
#pragma unroll
    for (int j = 0; j < 4; ++j) { float d = x[s][j] - mean; s2 += d * d; }
  float rs = rsqrtf(wave_sum(s2) * (1.0f / CC) + EPSF);
#pragma unroll
  for (int s = 0; s < 3; ++s) {
    int cc = s * 256 + c0;
    f32x4 gg = *(const f32x4*)(g + cc);
    f32x4 bb = *(const f32x4*)(b + cc);
    bf16x4 s4 = *(const bf16x4*)(sr + (size_t)row * CC + cc);
    bf16x4 o;
#pragma unroll
    for (int j = 0; j < 4; ++j)
      o[j] = (bf16_t)(((x[s][j] - mean) * rs * gg[j] + bb[j]) * (float)s4[j]);
    *(bf16x4*)(out + (size_t)row * CC + cc) = o;
  }
}

// ---------------- LN over HID=3072 rows -> bf16 ----------------
__global__ __launch_bounds__(256) void k_ln_hid(const float* __restrict__ in,
                                                const float* __restrict__ g,
                                                const float* __restrict__ b,
                                                bf16_t* __restrict__ out, int M) {
  int row = blockIdx.x * 4 + (threadIdx.x >> 6);
  if (row >= M) return;
  int lane = threadIdx.x & 63;
  const float* rp = in + (size_t)row * HD;
  int c0 = lane * 4;
  f32x4 x[12];
#pragma unroll
  for (int s = 0; s < 12; ++s) x[s] = *(const f32x4*)(rp + s * 256 + c0);
  float sum = 0.f;
#pragma unroll
  for (int s = 0; s < 12; ++s)
#pragma unroll
    for (int j = 0; j < 4; ++j) sum += x[s][j];
  float mean = wave_sum(sum) * (1.0f / HD);
  float s2 = 0.f;
#pragma unroll
  for (int s = 0; s < 12; ++s)
#pragma unroll
    for (int j = 0; j < 4; ++j) { float d = x[s][j] - mean; s2 += d * d; }
  float rs = rsqrtf(wave_sum(s2) * (1.0f / HD) + EPSF);
#pragma unroll
  for (int s = 0; s < 12; ++s) {
    int cc = s * 256 + c0;
    f32x4 gg = *(const f32x4*)(g + cc);
    f32x4 bb = *(const f32x4*)(b + cc);
    bf16x4 o;
#pragma unroll
    for (int j = 0; j < 4; ++j)
      o[j] = (bf16_t)((x[s][j] - mean) * rs * gg[j] + bb[j]);
    *(bf16x4*)(out + (size_t)row * HD + cc) = o;
  }
}

// ---------------- final: out = xb + sr_ffn * kv ----------------
__global__ __launch_bounds__(256) void k_final(const float* __restrict__ xb,
                                               const bf16_t* __restrict__ s,
                                               const float* __restrict__ kv,
                                               float* __restrict__ out, size_t n4) {
  size_t i = (size_t)blockIdx.x * 256 + threadIdx.x;
  if (i >= n4) return;
  f32x4 xv = *(const f32x4*)(xb + 4 * i);
  f32x4 kvv = *(const f32x4*)(kv + 4 * i);
  bf16x4 sv = *(const bf16x4*)(s + 4 * i);
  f32x4 o;
#pragma unroll
  for (int j = 0; j < 4; ++j) o[j] = xv[j] + (float)sv[j] * kvv[j];
  *(f32x4*)(out + 4 * i) = o;
}

// ---------------- host orchestration ----------------
struct Layout {
  size_t wk, wv, wr, wo, fk, fv, fr;
  size_t st, xb, g1, g2, b16, c16;
  size_t end;
};

static Layout make_layout(int CB) {
  Layout L;
  size_t off = 0;
  auto al = [&](size_t bytes) { size_t o = (off + 255) & ~(size_t)255; off = o + bytes; return o; };
  L.wk = al(589824ull * 2);
  L.wv = al(589824ull * 2);
  L.wr = al(589824ull * 2);
  L.wo = al(589824ull * 2);
  L.fk = al(2359296ull * 2);
  L.fv = al(2359296ull * 2);
  L.fr = al(589824ull * 2);
  size_t M = (size_t)CB * 196;
  size_t MC = M * 768;
  L.st  = al(M * 8);       // per-row (mean, rstd)
  L.xb  = al(MC * 4);      // residual stream f32
  L.g1  = al(MC * 16);     // K32|V32|P32|Q32  == KF32 (M x 3072 f32)
  L.g2  = al(MC * 8);      // R32|SR16|A16     == KF16 (M x 3072 bf16)
  L.b16 = al(MC * 2);
  L.c16 = al(MC * 2);
  L.end = off;
  return L;
}

extern "C" void kernel_launch(void* const* d_in, const int* in_sizes, int n_in,
                              void* d_out, int out_size, void* d_ws, size_t ws_size,
                              hipStream_t stream) {
  const float* x      = (const float*)d_in[0];
  const float* ln0_g  = (const float*)d_in[1];
  const float* ln0_b  = (const float*)d_in[2];
  const float* ln1_g  = (const float*)d_in[3];
  const float* ln1_b  = (const float*)d_in[4];
  const float* ln2_g  = (const float*)d_in[5];
  const float* ln2_b  = (const float*)d_in[6];
  const float* amk    = (const float*)d_in[7];
  const float* amv    = (const float*)d_in[8];
  const float* amr    = (const float*)d_in[9];
  const float* adec   = (const float*)d_in[10];
  const float* afirst = (const float*)d_in[11];
  const float* aWk    = (const float*)d_in[12];
  const float* aWv    = (const float*)d_in[13];
  const float* aWr    = (const float*)d_in[14];
  const float* aWo    = (const float*)d_in[15];
  const float* akn_g  = (const float*)d_in[16];
  const float* akn_b  = (const float*)d_in[17];
  const float* fmk    = (const float*)d_in[18];
  const float* fmr    = (const float*)d_in[19];
  const float* fWk    = (const float*)d_in[20];
  const float* fWv    = (const float*)d_in[21];
  const float* fWr    = (const float*)d_in[22];
  const float* fkn_g  = (const float*)d_in[23];
  const float* fkn_b  = (const float*)d_in[24];

  // pick largest batch-chunk that fits ws (whole pipeline is per-image independent)
  int CB = 32;
  {
    const int cands[3] = {128, 64, 32};
    for (int i = 0; i < 3; ++i) {
      if (make_layout(cands[i]).end <= ws_size) { CB = cands[i]; break; }
    }
  }
  Layout L = make_layout(CB);
  int nchunk = 128 / CB;
  int M = CB * 196;
  size_t MC = (size_t)M * 768;

  uint8_t* ws = (uint8_t*)d_ws;
  bf16_t* WkT = (bf16_t*)(ws + L.wk);
  bf16_t* WvT = (bf16_t*)(ws + L.wv);
  bf16_t* WrT = (bf16_t*)(ws + L.wr);
  bf16_t* WoT = (bf16_t*)(ws + L.wo);
  bf16_t* FkT = (bf16_t*)(ws + L.fk);
  bf16_t* FvT = (bf16_t*)(ws + L.fv);
  bf16_t* FrT = (bf16_t*)(ws + L.fr);
  float*  ST  = (float*)(ws + L.st);
  float*  XB  = (float*)(ws + L.xb);
  float*  K32 = (float*)(ws + L.g1);
  float*  V32 = K32 + MC;
  float*  P32 = K32 + 2 * MC;
  float*  Q32 = K32 + 3 * MC;
  float*  KF32 = K32;                               // M x 3072 f32
  float*  R32 = (float*)(ws + L.g2);
  bf16_t* SR16 = (bf16_t*)(ws + L.g2 + MC * 4);
  bf16_t* A16  = (bf16_t*)(ws + L.g2 + MC * 6);
  bf16_t* KF16 = (bf16_t*)(ws + L.g2);              // M x 3072 bf16
  bf16_t* B16  = (bf16_t*)(ws + L.b16);
  bf16_t* C16  = (bf16_t*)(ws + L.c16);

  // ---- weight convert + transpose (bf16, B^T layout) ----
  k_tcvt<<<dim3(24, 24), 256, 0, stream>>>(aWk, WkT, 768, 768);
  k_tcvt<<<dim3(24, 24), 256, 0, stream>>>(aWv, WvT, 768, 768);
  k_tcvt<<<dim3(24, 24), 256, 0, stream>>>(aWr, WrT, 768, 768);
  k_tcvt<<<dim3(24, 24), 256, 0, stream>>>(aWo, WoT, 768, 768);
  k_tcvt<<<dim3(96, 24), 256, 0, stream>>>(fWk, FkT, 768, 3072);   // (768,3072) -> (3072,768)
  k_tcvt<<<dim3(24, 96), 256, 0, stream>>>(fWv, FvT, 3072, 768);   // (3072,768) -> (768,3072)
  k_tcvt<<<dim3(24, 24), 256, 0, stream>>>(fWr, FrT, 768, 768);

  int rowb = M / 4;
  int Mt = M / 128;  // exact for CB in {32,64,128}
  dim3 g768(6, Mt), g3072(24, Mt);
  int wkvb = (CB * 768) / 256;

  for (int ch = 0; ch < nchunk; ++ch) {
    const float* xin = x + (size_t)ch * MC;
    float* outp = (float*)d_out + (size_t)ch * MC;

    // attention half
    k_ln0<<<rowb, 256, 0, stream>>>(xin, ln0_g, ln0_b, XB, ST, M);
    k_mix<3><<<rowb, 256, 0, stream>>>(XB, ST, ln1_g, ln1_b, amk, amv, amr, A16, B16, C16, M);
    k_gemm<EPI_F32><<<g768, 256, 0, stream>>>(A16, WkT, K32, M, 768, 768);
    k_gemm<EPI_F32><<<g768, 256, 0, stream>>>(B16, WvT, V32, M, 768, 768);
    k_gemm<EPI_SIG_BF16><<<g768, 256, 0, stream>>>(C16, WrT, SR16, M, 768, 768);
    k_wkv_bwd<<<wkvb, 256, 0, stream>>>(K32, V32, adec, P32, Q32, CB);
    k_wkv_fwd<<<wkvb, 256, 0, stream>>>(K32, V32, adec, afirst, P32, Q32, R32, CB);
    k_ln_mul<<<rowb, 256, 0, stream>>>(R32, SR16, akn_g, akn_b, A16, M);
    k_gemm<EPI_ADD><<<g768, 256, 0, stream>>>(A16, WoT, XB, M, 768, 768);

    // ffn half
    k_stats<<<rowb, 256, 0, stream>>>(XB, ST, M);
    k_mix<2><<<rowb, 256, 0, stream>>>(XB, ST, ln2_g, ln2_b, fmk, nullptr, fmr, A16, nullptr, C16, M);
    k_gemm<EPI_RELU2><<<g3072, 256, 0, stream>>>(A16, FkT, KF32, M, 3072, 768);
    k_gemm<EPI_SIG_BF16><<<g768, 256, 0, stream>>>(C16, FrT, B16, M, 768, 768);
    k_ln_hid<<<rowb, 256, 0, stream>>>(KF32, fkn_g, fkn_b, KF16, M);
    k_gemm<EPI_F32><<<g768, 256, 0, stream>>>(KF16, FvT, K32, M, 768, 3072);
    size_t n4 = MC / 4;
    k_final<<<(int)((n4 + 255) / 256), 256, 0, stream>>>(XB, B16, K32, outp, n4);
  }
}

// Round 2
// 1542.977 us; speedup vs baseline: 1.2328x; 1.2328x over previous
//
#include <hip/hip_runtime.h>
#include <stdint.h>

typedef __bf16 bf16_t;
typedef __bf16 bf16x8 __attribute__((ext_vector_type(8)));
typedef __bf16 bf16x4 __attribute__((ext_vector_type(4)));
typedef float f32x4 __attribute__((ext_vector_type(4)));
typedef unsigned short ushort_t;

#define CC 768
#define HD 3072
#define TB 196
#define HWD 14
#define EPSF 1e-5f
#define INV_T (1.0f/196.0f)

// ---------------- helpers ----------------
__device__ __forceinline__ float wave_sum(float v) {
#pragma unroll
  for (int off = 32; off > 0; off >>= 1) v += __shfl_xor(v, off, 64);
  return v;
}

__device__ __forceinline__ void async_copy16(const void* g, void* l) {
  typedef __attribute__((address_space(3))) uint32_t lds_u32;
  typedef __attribute__((address_space(1))) const uint32_t glb_u32;
  glb_u32* gp = (glb_u32*)(uintptr_t)g;
  lds_u32* lp = (lds_u32*)(uint32_t)(uintptr_t)l;
  __builtin_amdgcn_global_load_lds(gp, lp, 16, 0, 0);
}

// ---------------- LN0 (normalized row to XB + stats of output row) ----------------
__global__ __launch_bounds__(256) void k_ln0(const float* __restrict__ in,
                                             const float* __restrict__ g,
                                             const float* __restrict__ b,
                                             float* __restrict__ out,
                                             float* __restrict__ st, int M) {
  int row = blockIdx.x * 4 + (threadIdx.x >> 6);
  if (row >= M) return;
  int lane = threadIdx.x & 63;
  const float* rp = in + (size_t)row * CC;
  int c0 = lane * 4;
  f32x4 x[3];
#pragma unroll
  for (int s = 0; s < 3; ++s) x[s] = *(const f32x4*)(rp + s * 256 + c0);
  float sum = 0.f;
#pragma unroll
  for (int s = 0; s < 3; ++s)
#pragma unroll
    for (int j = 0; j < 4; ++j) sum += x[s][j];
  float mean = wave_sum(sum) * (1.0f / CC);
  float s2 = 0.f;
#pragma unroll
  for (int s = 0; s < 3; ++s)
#pragma unroll
    for (int j = 0; j < 4; ++j) { float d = x[s][j] - mean; s2 += d * d; }
  float rs = rsqrtf(wave_sum(s2) * (1.0f / CC) + EPSF);
  float* op = out + (size_t)row * CC;
  f32x4 o[3];
  float sum2 = 0.f;
#pragma unroll
  for (int s = 0; s < 3; ++s) {
    int cc = s * 256 + c0;
    f32x4 gg = *(const f32x4*)(g + cc);
    f32x4 bb = *(const f32x4*)(b + cc);
#pragma unroll
    for (int j = 0; j < 4; ++j) {
      o[s][j] = (x[s][j] - mean) * rs * gg[j] + bb[j];
      sum2 += o[s][j];
    }
    *(f32x4*)(op + cc) = o[s];
  }
  float mean2 = wave_sum(sum2) * (1.0f / CC);
  float q2 = 0.f;
#pragma unroll
  for (int s = 0; s < 3; ++s)
#pragma unroll
    for (int j = 0; j < 4; ++j) { float d = o[s][j] - mean2; q2 += d * d; }
  float rs2 = rsqrtf(wave_sum(q2) * (1.0f / CC) + EPSF);
  if (lane == 0) { st[2 * row] = mean2; st[2 * row + 1] = rs2; }
}

// ---------------- per-row mean/rstd ----------------
__global__ __launch_bounds__(256) void k_stats(const float* __restrict__ in,
                                               float* __restrict__ st, int M) {
  int row = blockIdx.x * 4 + (threadIdx.x >> 6);
  if (row >= M) return;
  int lane = threadIdx.x & 63;
  const float* rp = in + (size_t)row * CC;
  int c0 = lane * 4;
  f32x4 x[3];
#pragma unroll
  for (int s = 0; s < 3; ++s) x[s] = *(const f32x4*)(rp + s * 256 + c0);
  float sum = 0.f;
#pragma unroll
  for (int s = 0; s < 3; ++s)
#pragma unroll
    for (int j = 0; j < 4; ++j) sum += x[s][j];
  float mean = wave_sum(sum) * (1.0f / CC);
  float s2 = 0.f;
#pragma unroll
  for (int s = 0; s < 3; ++s)
#pragma unroll
    for (int j = 0; j < 4; ++j) { float d = x[s][j] - mean; s2 += d * d; }
  float rs = rsqrtf(wave_sum(s2) * (1.0f / CC) + EPSF);
  if (lane == 0) { st[2 * row] = mean; st[2 * row + 1] = rs; }
}

// ---------------- LN + q_shift + token-mix, bf16 outputs ----------------
template <int NOUT>
__global__ __launch_bounds__(256) void k_mix(const float* __restrict__ xb,
                                             const float* __restrict__ st,
                                             const float* __restrict__ g,
                                             const float* __restrict__ b,
                                             const float* __restrict__ mk,
                                             const float* __restrict__ mv,
                                             const float* __restrict__ mr,
                                             bf16_t* __restrict__ ok,
                                             bf16_t* __restrict__ ov,
                                             bf16_t* __restrict__ orr, int M) {
  int tok = blockIdx.x * 4 + (threadIdx.x >> 6);
  if (tok >= M) return;
  int lane = threadIdx.x & 63;
  int t = tok % TB;
  int h = t / HWD, w = t % HWD;
  int nbr[4];
  nbr[0] = (w > 0)       ? tok - 1   : -1;
  nbr[1] = (w < HWD - 1) ? tok + 1   : -1;
  nbr[2] = (h > 0)       ? tok - HWD : -1;
  nbr[3] = (h < HWD - 1) ? tok + HWD : -1;
  float ms = st[2 * tok], rss = st[2 * tok + 1];
  const float* rp = xb + (size_t)tok * CC;
#pragma unroll
  for (int s = 0; s < 3; ++s) {
    int cc = s * 256 + lane * 4;
    int grp = cc / 192;
    int nb = nbr[grp];
    f32x4 xs = *(const f32x4*)(rp + cc);
    f32x4 xn = {0.f, 0.f, 0.f, 0.f};
    float mn = 0.f, rsn = 0.f;
    if (nb >= 0) {
      xn = *(const f32x4*)(xb + (size_t)nb * CC + cc);
      mn = st[2 * nb];
      rsn = st[2 * nb + 1];
    }
    f32x4 gg = *(const f32x4*)(g + cc);
    f32x4 bb = *(const f32x4*)(b + cc);
    f32x4 mk4 = *(const f32x4*)(mk + cc);
    f32x4 mr4 = *(const f32x4*)(mr + cc);
    f32x4 mv4 = {0.f, 0.f, 0.f, 0.f};
    if (NOUT == 3) mv4 = *(const f32x4*)(mv + cc);
    bf16x4 vk, vv, vr;
#pragma unroll
    for (int j = 0; j < 4; ++j) {
      float xi = (xs[j] - ms) * rss * gg[j] + bb[j];
      float xx = (nb >= 0) ? ((xn[j] - mn) * rsn * gg[j] + bb[j]) : 0.f;
      vk[j] = (bf16_t)(xi * mk4[j] + xx * (1.0f - mk4[j]));
      if (NOUT == 3) vv[j] = (bf16_t)(xi * mv4[j] + xx * (1.0f - mv4[j]));
      vr[j] = (bf16_t)(xi * mr4[j] + xx * (1.0f - mr4[j]));
    }
    *(bf16x4*)(ok + (size_t)tok * CC + cc) = vk;
    if (NOUT == 3) *(bf16x4*)(ov + (size_t)tok * CC + cc) = vv;
    *(bf16x4*)(orr + (size_t)tok * CC + cc) = vr;
  }
}

// ---------------- weight f32 (K,N) -> bf16 transposed (N,K) ----------------
__global__ __launch_bounds__(256) void k_tcvt(const float* __restrict__ src,
                                              bf16_t* __restrict__ dst, int K, int N) {
  __shared__ float tile[32][33];
  int tx = threadIdx.x & 31;
  int ty = threadIdx.x >> 5;
  int n0 = blockIdx.x * 32, k0 = blockIdx.y * 32;
#pragma unroll
  for (int i = 0; i < 4; ++i)
    tile[ty + 8 * i][tx] = src[(size_t)(k0 + ty + 8 * i) * N + n0 + tx];
  __syncthreads();
#pragma unroll
  for (int i = 0; i < 4; ++i)
    dst[(size_t)(n0 + ty + 8 * i) * K + k0 + tx] = (bf16_t)tile[tx][ty + 8 * i];
}

// ---------------- MFMA GEMM ----------------
// BK=64, XOR-swizzled LDS (chunk ^= row&7 -> b128 reads hit the 8-touch/bank floor),
// XCD-aware block remap (all N-tiles of an M-row on one XCD -> A fetched once/XCD).
enum { EPI_F32 = 0, EPI_SIG_BF16 = 1, EPI_RELU2_BF16 = 2, EPI_ADD = 3, EPI_GATE = 4 };

struct GemmArgs {
  const bf16_t* A;
  const bf16_t* B;
  void* C;
  const bf16_t* gate;   // EPI_GATE
  const float* resid;   // EPI_GATE
  int epi;
};
struct GemmBatch { GemmArgs a[3]; };

__global__ __launch_bounds__(256) void k_gemm(GemmBatch batch, int M, int N, int K,
                                              int Mt, int NT) {
  __shared__ __align__(16) ushort_t As[128 * 64];
  __shared__ __align__(16) ushort_t Bs[128 * 64];
  GemmArgs ga = batch.a[blockIdx.z];
  int p = blockIdx.x;
  // XCD-aware remap: groups of 8 M-rows x NT N-tiles; same M-row => same (p%8) => same XCD
  int G = NT * 8;
  int Mt8 = Mt & ~7;
  int m, n;
  if (p < Mt8 * NT) {
    int g = p / G;
    int r = p - g * G;
    m = g * 8 + (r & 7);
    n = r >> 3;
  } else {
    int r2 = p - Mt8 * NT;
    int rem = Mt - Mt8;
    m = Mt8 + r2 % rem;
    n = r2 / rem;
  }
  int bm = m * 128, bn = n * 128;
  int tid = threadIdx.x;
  int wave = tid >> 6, lane = tid & 63;
  int lrow = lane >> 3;                       // 0..7 within an 8-row stripe
  int lchunk = (lane & 7) ^ (lrow & 7);       // swizzled source 16B-chunk
  int fr = lane & 15, fq = lane >> 4;
  int wm = (wave >> 1) * 64, wn = (wave & 1) * 64;
  int frs = fr & 7;                           // read-side swizzle key
  f32x4 acc[4][4] = {};
  const bf16_t* Ab = ga.A + (size_t)bm * K;
  const bf16_t* Bb = ga.B + (size_t)bn * K;
  for (int kt = 0; kt < K; kt += 64) {
#pragma unroll
    for (int j = 0; j < 4; ++j) {
      int r0 = j * 32 + wave * 8;
      async_copy16(Ab + (size_t)(r0 + lrow) * K + kt + lchunk * 8, As + r0 * 64);
      async_copy16(Bb + (size_t)(r0 + lrow) * K + kt + lchunk * 8, Bs + r0 * 64);
    }
    __syncthreads();
#pragma unroll
    for (int ks = 0; ks < 2; ++ks) {
      bf16x8 af[4], bfv[4];
#pragma unroll
      for (int i = 0; i < 4; ++i) {
        int ra = wm + i * 16 + fr;
        int rb = wn + i * 16 + fr;
        af[i]  = *(const bf16x8*)(As + ra * 64 + (((ks * 4 + fq) ^ frs) * 8));
        bfv[i] = *(const bf16x8*)(Bs + rb * 64 + (((ks * 4 + fq) ^ frs) * 8));
      }
#pragma unroll
      for (int mi = 0; mi < 4; ++mi)
#pragma unroll
        for (int ni = 0; ni < 4; ++ni)
          acc[mi][ni] = __builtin_amdgcn_mfma_f32_16x16x32_bf16(af[mi], bfv[ni], acc[mi][ni], 0, 0, 0);
    }
    __syncthreads();
  }
  int epi = ga.epi;
#pragma unroll
  for (int mi = 0; mi < 4; ++mi) {
#pragma unroll
    for (int ni = 0; ni < 4; ++ni) {
#pragma unroll
      for (int r = 0; r < 4; ++r) {
        int grow = bm + wm + mi * 16 + fq * 4 + r;
        int gcol = bn + wn + ni * 16 + fr;
        size_t idx = (size_t)grow * N + gcol;
        float v = acc[mi][ni][r];
        if (epi == EPI_F32) {
          ((float*)ga.C)[idx] = v;
        } else if (epi == EPI_SIG_BF16) {
          ((bf16_t*)ga.C)[idx] = (bf16_t)(1.0f / (1.0f + __expf(-v)));
        } else if (epi == EPI_RELU2_BF16) {
          float t = v > 0.f ? v : 0.f;
          ((bf16_t*)ga.C)[idx] = (bf16_t)(t * t);
        } else if (epi == EPI_ADD) {
          ((float*)ga.C)[idx] += v;
        } else {  // EPI_GATE: out = resid + sigmoid-gate * v
          ((float*)ga.C)[idx] = ga.resid[idx] + (float)ga.gate[idx] * v;
        }
      }
    }
  }
}

// ---------------- bidirectional WKV scans ----------------
__global__ __launch_bounds__(256) void k_wkv_bwd(const float* __restrict__ k,
                                                 const float* __restrict__ v,
                                                 const float* __restrict__ decay,
                                                 bf16_t* __restrict__ ba,
                                                 bf16_t* __restrict__ bb, int CB) {
  int idx = blockIdx.x * 256 + threadIdx.x;
  if (idx >= CB * CC) return;
  int c = idx % CC;
  size_t base = (size_t)(idx / CC) * TB * CC + c;
  float w = decay[c] * INV_T;
  float d = __expf(-w);
  float a = 0.f, bs = 0.f;
  for (int t = TB - 1; t >= 0; --t) {
    size_t p = base + (size_t)t * CC;
    ba[p] = (bf16_t)a;
    bb[p] = (bf16_t)bs;
    float ek = __expf(k[p]);
    a = d * (a + ek * v[p]);
    bs = d * (bs + ek);
  }
}

__global__ __launch_bounds__(256) void k_wkv_fwd(const float* __restrict__ k,
                                                 const float* __restrict__ v,
                                                 const float* __restrict__ decay,
                                                 const float* __restrict__ first,
                                                 const bf16_t* __restrict__ ba,
                                                 const bf16_t* __restrict__ bb,
                                                 bf16_t* __restrict__ r, int CB) {
  int idx = blockIdx.x * 256 + threadIdx.x;
  if (idx >= CB * CC) return;
  int c = idx % CC;
  size_t base = (size_t)(idx / CC) * TB * CC + c;
  float w = decay[c] * INV_T;
  float d = __expf(-w);
  float ew = __expf(w);
  float u = first[c] * INV_T;
  float a = 0.f, bs = 0.f;
  for (int t = 0; t < TB; ++t) {
    size_t p = base + (size_t)t * CC;
    float kk = k[p], vv = v[p];
    float eu = __expf(u + kk);
    float num = ew * (a + (float)ba[p]) + eu * vv;
    float den = ew * (bs + (float)bb[p]) + eu;
    r[p] = (bf16_t)(num / den);
    float ek = __expf(kk);
    a = d * (a + ek * vv);
    bs = d * (bs + ek);
  }
}

// ---------------- LN(rwkv bf16) * sr -> bf16 ----------------
__global__ __launch_bounds__(256) void k_ln_mul(const bf16_t* __restrict__ in,
                                                const bf16_t* __restrict__ sr,
                                                const float* __restrict__ g,
                                                const float* __restrict__ b,
                                                bf16_t* __restrict__ out, int M) {
  int row = blockIdx.x * 4 + (threadIdx.x >> 6);
  if (row >= M) return;
  int lane = threadIdx.x & 63;
  const bf16_t* rp = in + (size_t)row * CC;
  int c0 = lane * 4;
  float x[12];
#pragma unroll
  for (int s = 0; s < 3; ++s) {
    bf16x4 t = *(const bf16x4*)(rp + s * 256 + c0);
#pragma unroll
    for (int j = 0; j < 4; ++j) x[s * 4 + j] = (float)t[j];
  }
  float sum = 0.f;
#pragma unroll
  for (int i = 0; i < 12; ++i) sum += x[i];
  float mean = wave_sum(sum) * (1.0f / CC);
  float s2 = 0.f;
#pragma unroll
  for (int i = 0; i < 12; ++i) { float d = x[i] - mean; s2 += d * d; }
  float rs = rsqrtf(wave_sum(s2) * (1.0f / CC) + EPSF);
#pragma unroll
  for (int s = 0; s < 3; ++s) {
    int cc = s * 256 + c0;
    f32x4 gg = *(const f32x4*)(g + cc);
    f32x4 bb = *(const f32x4*)(b + cc);
    bf16x4 s4 = *(const bf16x4*)(sr + (size_t)row * CC + cc);
    bf16x4 o;
#pragma unroll
    for (int j = 0; j < 4; ++j)
      o[j] = (bf16_t)(((x[s * 4 + j] - mean) * rs * gg[j] + bb[j]) * (float)s4[j]);
    *(bf16x4*)(out + (size_t)row * CC + cc) = o;
  }
}

// ---------------- LN over HID=3072 bf16 rows -> bf16 ----------------
__global__ __launch_bounds__(256) void k_ln_hid(const bf16_t* __restrict__ in,
                                                const float* __restrict__ g,
                                                const float* __restrict__ b,
                                                bf16_t* __restrict__ out, int M) {
  int row = blockIdx.x * 4 + (threadIdx.x >> 6);
  if (row >= M) return;
  int lane = threadIdx.x & 63;
  const bf16_t* rp = in + (size_t)row * HD;
  int c0 = lane * 8;
  bf16x8 x[6];
#pragma unroll
  for (int s = 0; s < 6; ++s) x[s] = *(const bf16x8*)(rp + s * 512 + c0);
  float sum = 0.f;
#pragma unroll
  for (int s = 0; s < 6; ++s)
#pragma unroll
    for (int j = 0; j < 8; ++j) sum += (float)x[s][j];
  float mean = wave_sum(sum) * (1.0f / HD);
  float s2 = 0.f;
#pragma unroll
  for (int s = 0; s < 6; ++s)
#pragma unroll
    for (int j = 0; j < 8; ++j) { float d = (float)x[s][j] - mean; s2 += d * d; }
  float rs = rsqrtf(wave_sum(s2) * (1.0f / HD) + EPSF);
#pragma unroll
  for (int s = 0; s < 6; ++s) {
    int cc = s * 512 + c0;
    f32x4 g0 = *(const f32x4*)(g + cc);
    f32x4 g1 = *(const f32x4*)(g + cc + 4);
    f32x4 b0 = *(const f32x4*)(b + cc);
    f32x4 b1 = *(const f32x4*)(b + cc + 4);
    bf16x8 o;
#pragma unroll
    for (int j = 0; j < 4; ++j) {
      o[j]     = (bf16_t)(((float)x[s][j]     - mean) * rs * g0[j] + b0[j]);
      o[j + 4] = (bf16_t)(((float)x[s][j + 4] - mean) * rs * g1[j] + b1[j]);
    }
    *(bf16x8*)(out + (size_t)row * HD + cc) = o;
  }
}

// ---------------- host orchestration ----------------
struct Layout {
  size_t wk, wv, wr, wo, fk, fv, fr;
  size_t st, big, a16, b16, c16;
  size_t end;
};

static Layout make_layout(int CB) {
  Layout L;
  size_t off = 0;
  auto al = [&](size_t bytes) { size_t o = (off + 255) & ~(size_t)255; off = o + bytes; return o; };
  L.wk = al(589824ull * 2);
  L.wv = al(589824ull * 2);
  L.wr = al(589824ull * 2);
  L.wo = al(589824ull * 2);
  L.fk = al(2359296ull * 2);
  L.fv = al(2359296ull * 2);
  L.fr = al(589824ull * 2);
  size_t M = (size_t)CB * 196;
  size_t MC = M * 768;
  L.st  = al(M * 8);
  L.big = al(MC * 16);   // union: [K32|V32|P16|Q16|R16|SR16] vs [KFa|KFb]
  L.a16 = al(MC * 2);
  L.b16 = al(MC * 2);
  L.c16 = al(MC * 2);
  L.end = off;
  return L;
}

extern "C" void kernel_launch(void* const* d_in, const int* in_sizes, int n_in,
                              void* d_out, int out_size, void* d_ws, size_t ws_size,
                              hipStream_t stream) {
  const float* x      = (const float*)d_in[0];
  const float* ln0_g  = (const float*)d_in[1];
  const float* ln0_b  = (const float*)d_in[2];
  const float* ln1_g  = (const float*)d_in[3];
  const float* ln1_b  = (const float*)d_in[4];
  const float* ln2_g  = (const float*)d_in[5];
  const float* ln2_b  = (const float*)d_in[6];
  const float* amk    = (const float*)d_in[7];
  const float* amv    = (const float*)d_in[8];
  const float* amr    = (const float*)d_in[9];
  const float* adec   = (const float*)d_in[10];
  const float* afirst = (const float*)d_in[11];
  const float* aWk    = (const float*)d_in[12];
  const float* aWv    = (const float*)d_in[13];
  const float* aWr    = (const float*)d_in[14];
  const float* aWo    = (const float*)d_in[15];
  const float* akn_g  = (const float*)d_in[16];
  const float* akn_b  = (const float*)d_in[17];
  const float* fmk    = (const float*)d_in[18];
  const float* fmr    = (const float*)d_in[19];
  const float* fWk    = (const float*)d_in[20];
  const float* fWv    = (const float*)d_in[21];
  const float* fWr    = (const float*)d_in[22];
  const float* fkn_g  = (const float*)d_in[23];
  const float* fkn_b  = (const float*)d_in[24];

  int CB = 32;
  {
    const int cands[3] = {128, 64, 32};
    for (int i = 0; i < 3; ++i)
      if (make_layout(cands[i]).end <= ws_size) { CB = cands[i]; break; }
  }
  Layout L = make_layout(CB);
  int nchunk = 128 / CB;
  int M = CB * 196;
  size_t MC = (size_t)M * 768;

  uint8_t* ws = (uint8_t*)d_ws;
  bf16_t* WkT = (bf16_t*)(ws + L.wk);
  bf16_t* WvT = (bf16_t*)(ws + L.wv);
  bf16_t* WrT = (bf16_t*)(ws + L.wr);
  bf16_t* WoT = (bf16_t*)(ws + L.wo);
  bf16_t* FkT = (bf16_t*)(ws + L.fk);
  bf16_t* FvT = (bf16_t*)(ws + L.fv);
  bf16_t* FrT = (bf16_t*)(ws + L.fr);
  float*  ST  = (float*)(ws + L.st);
  uint8_t* big = ws + L.big;
  float*  K32 = (float*)(big);
  float*  V32 = (float*)(big + MC * 4);
  bf16_t* P16 = (bf16_t*)(big + MC * 8);
  bf16_t* Q16 = (bf16_t*)(big + MC * 10);
  bf16_t* R16 = (bf16_t*)(big + MC * 12);
  bf16_t* SR16 = (bf16_t*)(big + MC * 14);
  bf16_t* KFa = (bf16_t*)(big);            // M x 3072 bf16 (aliases K32..Q16, dead by then)
  bf16_t* KFb = (bf16_t*)(big + MC * 8);   // M x 3072 bf16
  bf16_t* A16 = (bf16_t*)(ws + L.a16);
  bf16_t* B16 = (bf16_t*)(ws + L.b16);
  bf16_t* C16 = (bf16_t*)(ws + L.c16);

  k_tcvt<<<dim3(24, 24), 256, 0, stream>>>(aWk, WkT, 768, 768);
  k_tcvt<<<dim3(24, 24), 256, 0, stream>>>(aWv, WvT, 768, 768);
  k_tcvt<<<dim3(24, 24), 256, 0, stream>>>(aWr, WrT, 768, 768);
  k_tcvt<<<dim3(24, 24), 256, 0, stream>>>(aWo, WoT, 768, 768);
  k_tcvt<<<dim3(96, 24), 256, 0, stream>>>(fWk, FkT, 768, 3072);
  k_tcvt<<<dim3(24, 96), 256, 0, stream>>>(fWv, FvT, 3072, 768);
  k_tcvt<<<dim3(24, 24), 256, 0, stream>>>(fWr, FrT, 768, 768);

  int rowb = M / 4;
  int Mt = M / 128;
  int wkvb = (CB * 768) / 256;

  for (int ch = 0; ch < nchunk; ++ch) {
    const float* xin = x + (size_t)ch * MC;
    float* XB = (float*)d_out + (size_t)ch * MC;   // residual stream lives in d_out

    // ---- attention half ----
    k_ln0<<<rowb, 256, 0, stream>>>(xin, ln0_g, ln0_b, XB, ST, M);
    k_mix<3><<<rowb, 256, 0, stream>>>(XB, ST, ln1_g, ln1_b, amk, amv, amr, A16, B16, C16, M);
    {
      GemmBatch gb{};
      gb.a[0] = {A16, WkT, K32, nullptr, nullptr, EPI_F32};
      gb.a[1] = {B16, WvT, V32, nullptr, nullptr, EPI_F32};
      gb.a[2] = {C16, WrT, SR16, nullptr, nullptr, EPI_SIG_BF16};
      k_gemm<<<dim3(6 * Mt, 1, 3), 256, 0, stream>>>(gb, M, 768, 768, Mt, 6);
    }
    k_wkv_bwd<<<wkvb, 256, 0, stream>>>(K32, V32, adec, P16, Q16, CB);
    k_wkv_fwd<<<wkvb, 256, 0, stream>>>(K32, V32, adec, afirst, P16, Q16, R16, CB);
    k_ln_mul<<<rowb, 256, 0, stream>>>(R16, SR16, akn_g, akn_b, A16, M);
    {
      GemmBatch gb{};
      gb.a[0] = {A16, WoT, XB, nullptr, nullptr, EPI_ADD};
      k_gemm<<<dim3(6 * Mt, 1, 1), 256, 0, stream>>>(gb, M, 768, 768, Mt, 6);
    }

    // ---- ffn half ----
    k_stats<<<rowb, 256, 0, stream>>>(XB, ST, M);
    k_mix<2><<<rowb, 256, 0, stream>>>(XB, ST, ln2_g, ln2_b, fmk, nullptr, fmr, A16, nullptr, C16, M);
    {
      GemmBatch gb{};
      gb.a[0] = {A16, FkT, KFa, nullptr, nullptr, EPI_RELU2_BF16};
      k_gemm<<<dim3(24 * Mt, 1, 1), 256, 0, stream>>>(gb, M, 3072, 768, Mt, 24);
    }
    {
      GemmBatch gb{};
      gb.a[0] = {C16, FrT, B16, nullptr, nullptr, EPI_SIG_BF16};
      k_gemm<<<dim3(6 * Mt, 1, 1), 256, 0, stream>>>(gb, M, 768, 768, Mt, 6);
    }
    k_ln_hid<<<rowb, 256, 0, stream>>>(KFa, fkn_g, fkn_b, KFb, M);
    {
      GemmBatch gb{};
      gb.a[0] = {KFb, FvT, XB, B16, XB, EPI_GATE};
      k_gemm<<<dim3(6 * Mt, 1, 1), 256, 0, stream>>>(gb, M, 768, 3072, Mt, 6);
    }
  }
}

// Round 4
// 1268.830 us; speedup vs baseline: 1.4991x; 1.2161x over previous
//
#include <hip/hip_runtime.h>
#include <stdint.h>

typedef __bf16 bf16_t;
typedef __bf16 bf16x8 __attribute__((ext_vector_type(8)));
typedef __bf16 bf16x4 __attribute__((ext_vector_type(4)));
typedef float f32x4 __attribute__((ext_vector_type(4)));
typedef unsigned short ushort_t;

#define CC 768
#define HD 3072
#define TB 196
#define HWD 14
#define EPSF 1e-5f
#define INV_T (1.0f/196.0f)

// ---------------- helpers ----------------
__device__ __forceinline__ float wave_sum(float v) {
#pragma unroll
  for (int off = 32; off > 0; off >>= 1) v += __shfl_xor(v, off, 64);
  return v;
}

__device__ __forceinline__ void async_copy16(const void* g, void* l) {
  typedef __attribute__((address_space(3))) uint32_t lds_u32;
  typedef __attribute__((address_space(1))) const uint32_t glb_u32;
  glb_u32* gp = (glb_u32*)(uintptr_t)g;
  lds_u32* lp = (lds_u32*)(uint32_t)(uintptr_t)l;
  __builtin_amdgcn_global_load_lds(gp, lp, 16, 0, 0);
}

// compiler-only scheduling fence: keeps each stage's 4 global_load_lds
// contiguous in program order so s_waitcnt vmcnt(4) group-counting is exact.
#define SCHED_FENCE() asm volatile("" ::: "memory")

// ---------------- LN0 (normalized row to XB + stats of output row) ----------------
__global__ __launch_bounds__(256) void k_ln0(const float* __restrict__ in,
                                             const float* __restrict__ g,
                                             const float* __restrict__ b,
                                             float* __restrict__ out,
                                             float* __restrict__ st, int M) {
  int row = blockIdx.x * 4 + (threadIdx.x >> 6);
  if (row >= M) return;
  int lane = threadIdx.x & 63;
  const float* rp = in + (size_t)row * CC;
  int c0 = lane * 4;
  f32x4 x[3];
#pragma unroll
  for (int s = 0; s < 3; ++s) x[s] = *(const f32x4*)(rp + s * 256 + c0);
  float sum = 0.f;
#pragma unroll
  for (int s = 0; s < 3; ++s)
#pragma unroll
    for (int j = 0; j < 4; ++j) sum += x[s][j];
  float mean = wave_sum(sum) * (1.0f / CC);
  float s2 = 0.f;
#pragma unroll
  for (int s = 0; s < 3; ++s)
#pragma unroll
    for (int j = 0; j < 4; ++j) { float d = x[s][j] - mean; s2 += d * d; }
  float rs = rsqrtf(wave_sum(s2) * (1.0f / CC) + EPSF);
  float* op = out + (size_t)row * CC;
  f32x4 o[3];
  float sum2 = 0.f;
#pragma unroll
  for (int s = 0; s < 3; ++s) {
    int cc = s * 256 + c0;
    f32x4 gg = *(const f32x4*)(g + cc);
    f32x4 bb = *(const f32x4*)(b + cc);
#pragma unroll
    for (int j = 0; j < 4; ++j) {
      o[s][j] = (x[s][j] - mean) * rs * gg[j] + bb[j];
      sum2 += o[s][j];
    }
    *(f32x4*)(op + cc) = o[s];
  }
  float mean2 = wave_sum(sum2) * (1.0f / CC);
  float q2 = 0.f;
#pragma unroll
  for (int s = 0; s < 3; ++s)
#pragma unroll
    for (int j = 0; j < 4; ++j) { float d = o[s][j] - mean2; q2 += d * d; }
  float rs2 = rsqrtf(wave_sum(q2) * (1.0f / CC) + EPSF);
  if (lane == 0) { st[2 * row] = mean2; st[2 * row + 1] = rs2; }
}

// ---------------- per-row mean/rstd ----------------
__global__ __launch_bounds__(256) void k_stats(const float* __restrict__ in,
                                               float* __restrict__ st, int M) {
  int row = blockIdx.x * 4 + (threadIdx.x >> 6);
  if (row >= M) return;
  int lane = threadIdx.x & 63;
  const float* rp = in + (size_t)row * CC;
  int c0 = lane * 4;
  f32x4 x[3];
#pragma unroll
  for (int s = 0; s < 3; ++s) x[s] = *(const f32x4*)(rp + s * 256 + c0);
  float sum = 0.f;
#pragma unroll
  for (int s = 0; s < 3; ++s)
#pragma unroll
    for (int j = 0; j < 4; ++j) sum += x[s][j];
  float mean = wave_sum(sum) * (1.0f / CC);
  float s2 = 0.f;
#pragma unroll
  for (int s = 0; s < 3; ++s)
#pragma unroll
    for (int j = 0; j < 4; ++j) { float d = x[s][j] - mean; s2 += d * d; }
  float rs = rsqrtf(wave_sum(s2) * (1.0f / CC) + EPSF);
  if (lane == 0) { st[2 * row] = mean; st[2 * row + 1] = rs; }
}

// ---------------- LN + q_shift + token-mix, bf16 outputs ----------------
template <int NOUT>
__global__ __launch_bounds__(256) void k_mix(const float* __restrict__ xb,
                                             const float* __restrict__ st,
                                             const float* __restrict__ g,
                                             const float* __restrict__ b,
                                             const float* __restrict__ mk,
                                             const float* __restrict__ mv,
                                             const float* __restrict__ mr,
                                             bf16_t* __restrict__ ok,
                                             bf16_t* __restrict__ ov,
                                             bf16_t* __restrict__ orr, int M) {
  int tok = blockIdx.x * 4 + (threadIdx.x >> 6);
  if (tok >= M) return;
  int lane = threadIdx.x & 63;
  int t = tok % TB;
  int h = t / HWD, w = t % HWD;
  int nbr[4];
  nbr[0] = (w > 0)       ? tok - 1   : -1;
  nbr[1] = (w < HWD - 1) ? tok + 1   : -1;
  nbr[2] = (h > 0)       ? tok - HWD : -1;
  nbr[3] = (h < HWD - 1) ? tok + HWD : -1;
  float ms = st[2 * tok], rss = st[2 * tok + 1];
  const float* rp = xb + (size_t)tok * CC;
#pragma unroll
  for (int s = 0; s < 3; ++s) {
    int cc = s * 256 + lane * 4;
    int grp = cc / 192;
    int nb = nbr[grp];
    f32x4 xs = *(const f32x4*)(rp + cc);
    f32x4 xn = {0.f, 0.f, 0.f, 0.f};
    float mn = 0.f, rsn = 0.f;
    if (nb >= 0) {
      xn = *(const f32x4*)(xb + (size_t)nb * CC + cc);
      mn = st[2 * nb];
      rsn = st[2 * nb + 1];
    }
    f32x4 gg = *(const f32x4*)(g + cc);
    f32x4 bb = *(const f32x4*)(b + cc);
    f32x4 mk4 = *(const f32x4*)(mk + cc);
    f32x4 mr4 = *(const f32x4*)(mr + cc);
    f32x4 mv4 = {0.f, 0.f, 0.f, 0.f};
    if (NOUT == 3) mv4 = *(const f32x4*)(mv + cc);
    bf16x4 vk, vv, vr;
#pragma unroll
    for (int j = 0; j < 4; ++j) {
      float xi = (xs[j] - ms) * rss * gg[j] + bb[j];
      float xx = (nb >= 0) ? ((xn[j] - mn) * rsn * gg[j] + bb[j]) : 0.f;
      vk[j] = (bf16_t)(xi * mk4[j] + xx * (1.0f - mk4[j]));
      if (NOUT == 3) vv[j] = (bf16_t)(xi * mv4[j] + xx * (1.0f - mv4[j]));
      vr[j] = (bf16_t)(xi * mr4[j] + xx * (1.0f - mr4[j]));
    }
    *(bf16x4*)(ok + (size_t)tok * CC + cc) = vk;
    if (NOUT == 3) *(bf16x4*)(ov + (size_t)tok * CC + cc) = vv;
    *(bf16x4*)(orr + (size_t)tok * CC + cc) = vr;
  }
}

// ---------------- weight f32 (K,N) -> bf16 transposed (N,K) ----------------
__global__ __launch_bounds__(256) void k_tcvt(const float* __restrict__ src,
                                              bf16_t* __restrict__ dst, int K, int N) {
  __shared__ float tile[32][33];
  int tx = threadIdx.x & 31;
  int ty = threadIdx.x >> 5;
  int n0 = blockIdx.x * 32, k0 = blockIdx.y * 32;
#pragma unroll
  for (int i = 0; i < 4; ++i)
    tile[ty + 8 * i][tx] = src[(size_t)(k0 + ty + 8 * i) * N + n0 + tx];
  __syncthreads();
#pragma unroll
  for (int i = 0; i < 4; ++i)
    dst[(size_t)(n0 + ty + 8 * i) * K + k0 + tx] = (bf16_t)tile[tx][ty + 8 * i];
}

// ---------------- MFMA GEMM ----------------
// BK=32, 3-stage LDS ring (48 KB), prefetch distance 2, one raw s_barrier/iter,
// s_waitcnt vmcnt(4) (never drains the prefetch queue until the last iter).
// Stage groups are fenced so vmcnt group-counting is exact.
enum { EPI_F32 = 0, EPI_SIG_BF16 = 1, EPI_RELU2_BF16 = 2, EPI_ADD = 3, EPI_GATE = 4 };

struct GemmArgs {
  const bf16_t* A;
  const bf16_t* B;
  void* C;
  const bf16_t* gate;   // EPI_GATE
  const float* resid;   // EPI_GATE
  int epi;
};
struct GemmBatch { GemmArgs a[3]; };

__global__ __launch_bounds__(256) void k_gemm(GemmBatch batch, int M, int N, int K,
                                              int Mt, int NT) {
  __shared__ __align__(16) ushort_t sA[3][128 * 32];
  __shared__ __align__(16) ushort_t sB[3][128 * 32];
  GemmArgs ga = batch.a[blockIdx.z];
  int p = blockIdx.x;
  int G = NT * 8;
  int Mt8 = Mt & ~7;
  int m, n;
  if (p < Mt8 * NT) {
    int g = p / G;
    int r = p - g * G;
    m = g * 8 + (r & 7);
    n = r >> 3;
  } else {
    int r2 = p - Mt8 * NT;
    int rem = Mt - Mt8;
    m = Mt8 + r2 % rem;
    n = r2 / rem;
  }
  int bm = m * 128, bn = n * 128;
  int tid = threadIdx.x;
  int wave = tid >> 6, lane = tid & 63;
  int lrow = lane >> 2;      // 0..15: row within a 16-row staging stripe
  int lchunk = lane & 3;     // 16B chunk within a 64B row
  int fr = lane & 15, fq = lane >> 4;
  int wm = (wave >> 1) * 64, wn = (wave & 1) * 64;
  const bf16_t* Ab = ga.A + (size_t)bm * K;
  const bf16_t* Bb = ga.B + (size_t)bn * K;

  auto stage = [&](int ktile, int s) {
#pragma unroll
    for (int j = 0; j < 2; ++j) {
      int r0 = j * 64 + wave * 16;
      int row = r0 + lrow;
      int sc = ((lchunk ^ ((row >> 1) & 3)) * 8) + ktile * 32;  // swizzled src col (bf16)
      async_copy16(Ab + (size_t)row * K + sc, &sA[s][r0 * 32]);
      async_copy16(Bb + (size_t)row * K + sc, &sB[s][r0 * 32]);
    }
  };

  int niter = K >> 5;
  stage(0, 0);
  SCHED_FENCE();
  stage(1, 1);
  SCHED_FENCE();
  int sc_cons = 0;
  f32x4 acc[4][4] = {};
  for (int i = 0; i < niter; ++i) {
    // my stage-i copies were issued 2 iters ago -> retired; keep stage i+1 in flight
    if (i < niter - 1) asm volatile("s_waitcnt vmcnt(4)" ::: "memory");
    else               asm volatile("s_waitcnt vmcnt(0)" ::: "memory");
    asm volatile("s_barrier" ::: "memory");  // all waves' stage-i data now in LDS
    if (i + 2 < niter) {
      int s2 = sc_cons - 1; if (s2 < 0) s2 = 2;   // (i+2)%3
      stage(i + 2, s2);
    }
    SCHED_FENCE();
    bf16x8 af[4], bfv[4];
#pragma unroll
    for (int t = 0; t < 4; ++t) {
      int ra = wm + t * 16 + fr;
      int rb = wn + t * 16 + fr;
      af[t]  = *(const bf16x8*)&sA[sc_cons][ra * 32 + ((fq ^ ((ra >> 1) & 3)) * 8)];
      bfv[t] = *(const bf16x8*)&sB[sc_cons][rb * 32 + ((fq ^ ((rb >> 1) & 3)) * 8)];
    }
#pragma unroll
    for (int mi = 0; mi < 4; ++mi)
#pragma unroll
      for (int ni = 0; ni < 4; ++ni)
        acc[mi][ni] = __builtin_amdgcn_mfma_f32_16x16x32_bf16(af[mi], bfv[ni], acc[mi][ni], 0, 0, 0);
    sc_cons = (sc_cons == 2) ? 0 : sc_cons + 1;
  }
  int epi = ga.epi;
#pragma unroll
  for (int mi = 0; mi < 4; ++mi) {
#pragma unroll
    for (int ni = 0; ni < 4; ++ni) {
#pragma unroll
      for (int r = 0; r < 4; ++r) {
        int grow = bm + wm + mi * 16 + fq * 4 + r;
        int gcol = bn + wn + ni * 16 + fr;
        size_t idx = (size_t)grow * N + gcol;
        float v = acc[mi][ni][r];
        if (epi == EPI_F32) {
          ((float*)ga.C)[idx] = v;
        } else if (epi == EPI_SIG_BF16) {
          ((bf16_t*)ga.C)[idx] = (bf16_t)(1.0f / (1.0f + __expf(-v)));
        } else if (epi == EPI_RELU2_BF16) {
          float t = v > 0.f ? v : 0.f;
          ((bf16_t*)ga.C)[idx] = (bf16_t)(t * t);
        } else if (epi == EPI_ADD) {
          ((float*)ga.C)[idx] += v;
        } else {  // EPI_GATE: out = resid + sigmoid-gate * v
          ((float*)ga.C)[idx] = ga.resid[idx] + (float)ga.gate[idx] * v;
        }
      }
    }
  }
}

// ---------------- bidirectional WKV scans ----------------
__global__ __launch_bounds__(256) void k_wkv_bwd(const float* __restrict__ k,
                                                 const float* __restrict__ v,
                                                 const float* __restrict__ decay,
                                                 bf16_t* __restrict__ ba,
                                                 bf16_t* __restrict__ bb, int CB) {
  int idx = blockIdx.x * 256 + threadIdx.x;
  if (idx >= CB * CC) return;
  int c = idx % CC;
  size_t base = (size_t)(idx / CC) * TB * CC + c;
  float w = decay[c] * INV_T;
  float d = __expf(-w);
  float a = 0.f, bs = 0.f;
  for (int t = TB - 1; t >= 0; --t) {
    size_t p = base + (size_t)t * CC;
    ba[p] = (bf16_t)a;
    bb[p] = (bf16_t)bs;
    float ek = __expf(k[p]);
    a = d * (a + ek * v[p]);
    bs = d * (bs + ek);
  }
}

__global__ __launch_bounds__(256) void k_wkv_fwd(const float* __restrict__ k,
                                                 const float* __restrict__ v,
                                                 const float* __restrict__ decay,
                                                 const float* __restrict__ first,
                                                 const bf16_t* __restrict__ ba,
                                                 const bf16_t* __restrict__ bb,
                                                 bf16_t* __restrict__ r, int CB) {
  int idx = blockIdx.x * 256 + threadIdx.x;
  if (idx >= CB * CC) return;
  int c = idx % CC;
  size_t base = (size_t)(idx / CC) * TB * CC + c;
  float w = decay[c] * INV_T;
  float d = __expf(-w);
  float ew = __expf(w);
  float u = first[c] * INV_T;
  float a = 0.f, bs = 0.f;
  for (int t = 0; t < TB; ++t) {
    size_t p = base + (size_t)t * CC;
    float kk = k[p], vv = v[p];
    float eu = __expf(u + kk);
    float num = ew * (a + (float)ba[p]) + eu * vv;
    float den = ew * (bs + (float)bb[p]) + eu;
    r[p] = (bf16_t)(num / den);
    float ek = __expf(kk);
    a = d * (a + ek * vv);
    bs = d * (bs + ek);
  }
}

// ---------------- LN(rwkv bf16) * sr -> bf16 ----------------
__global__ __launch_bounds__(256) void k_ln_mul(const bf16_t* __restrict__ in,
                                                const bf16_t* __restrict__ sr,
                                                const float* __restrict__ g,
                                                const float* __restrict__ b,
                                                bf16_t* __restrict__ out, int M) {
  int row = blockIdx.x * 4 + (threadIdx.x >> 6);
  if (row >= M) return;
  int lane = threadIdx.x & 63;
  const bf16_t* rp = in + (size_t)row * CC;
  int c0 = lane * 4;
  float x[12];
#pragma unroll
  for (int s = 0; s < 3; ++s) {
    bf16x4 t = *(const bf16x4*)(rp + s * 256 + c0);
#pragma unroll
    for (int j = 0; j < 4; ++j) x[s * 4 + j] = (float)t[j];
  }
  float sum = 0.f;
#pragma unroll
  for (int i = 0; i < 12; ++i) sum += x[i];
  float mean = wave_sum(sum) * (1.0f / CC);
  float s2 = 0.f;
#pragma unroll
  for (int i = 0; i < 12; ++i) { float d = x[i] - mean; s2 += d * d; }
  float rs = rsqrtf(wave_sum(s2) * (1.0f / CC) + EPSF);
#pragma unroll
  for (int s = 0; s < 3; ++s) {
    int cc = s * 256 + c0;
    f32x4 gg = *(const f32x4*)(g + cc);
    f32x4 bb = *(const f32x4*)(b + cc);
    bf16x4 s4 = *(const bf16x4*)(sr + (size_t)row * CC + cc);
    bf16x4 o;
#pragma unroll
    for (int j = 0; j < 4; ++j)
      o[j] = (bf16_t)(((x[s * 4 + j] - mean) * rs * gg[j] + bb[j]) * (float)s4[j]);
    *(bf16x4*)(out + (size_t)row * CC + cc) = o;
  }
}

// ---------------- LN over HID=3072 bf16 rows -> bf16 ----------------
__global__ __launch_bounds__(256) void k_ln_hid(const bf16_t* __restrict__ in,
                                                const float* __restrict__ g,
                                                const float* __restrict__ b,
                                                bf16_t* __restrict__ out, int M) {
  int row = blockIdx.x * 4 + (threadIdx.x >> 6);
  if (row >= M) return;
  int lane = threadIdx.x & 63;
  const bf16_t* rp = in + (size_t)row * HD;
  int c0 = lane * 8;
  bf16x8 x[6];
#pragma unroll
  for (int s = 0; s < 6; ++s) x[s] = *(const bf16x8*)(rp + s * 512 + c0);
  float sum = 0.f;
#pragma unroll
  for (int s = 0; s < 6; ++s)
#pragma unroll
    for (int j = 0; j < 8; ++j) sum += (float)x[s][j];
  float mean = wave_sum(sum) * (1.0f / HD);
  float s2 = 0.f;
#pragma unroll
  for (int s = 0; s < 6; ++s)
#pragma unroll
    for (int j = 0; j < 8; ++j) { float d = (float)x[s][j] - mean; s2 += d * d; }
  float rs = rsqrtf(wave_sum(s2) * (1.0f / HD) + EPSF);
#pragma unroll
  for (int s = 0; s < 6; ++s) {
    int cc = s * 512 + c0;
    f32x4 g0 = *(const f32x4*)(g + cc);
    f32x4 g1 = *(const f32x4*)(g + cc + 4);
    f32x4 b0 = *(const f32x4*)(b + cc);
    f32x4 b1 = *(const f32x4*)(b + cc + 4);
    bf16x8 o;
#pragma unroll
    for (int j = 0; j < 4; ++j) {
      o[j]     = (bf16_t)(((float)x[s][j]     - mean) * rs * g0[j] + b0[j]);
      o[j + 4] = (bf16_t)(((float)x[s][j + 4] - mean) * rs * g1[j] + b1[j]);
    }
    *(bf16x8*)(out + (size_t)row * HD + cc) = o;
  }
}

// ---------------- host orchestration ----------------
struct Layout {
  size_t wk, wv, wr, wo, fk, fv, fr;
  size_t st, big, a16, b16, c16;
  size_t end;
};

static Layout make_layout(int CB) {
  Layout L;
  size_t off = 0;
  auto al = [&](size_t bytes) { size_t o = (off + 255) & ~(size_t)255; off = o + bytes; return o; };
  L.wk = al(589824ull * 2);
  L.wv = al(589824ull * 2);
  L.wr = al(589824ull * 2);
  L.wo = al(589824ull * 2);
  L.fk = al(2359296ull * 2);
  L.fv = al(2359296ull * 2);
  L.fr = al(589824ull * 2);
  size_t M = (size_t)CB * 196;
  size_t MC = M * 768;
  L.st  = al(M * 8);
  L.big = al(MC * 16);   // union: [K32|V32|P16|Q16|R16|SR16] vs [KFa|KFb]
  L.a16 = al(MC * 2);
  L.b16 = al(MC * 2);
  L.c16 = al(MC * 2);
  L.end = off;
  return L;
}

extern "C" void kernel_launch(void* const* d_in, const int* in_sizes, int n_in,
                              void* d_out, int out_size, void* d_ws, size_t ws_size,
                              hipStream_t stream) {
  const float* x      = (const float*)d_in[0];
  const float* ln0_g  = (const float*)d_in[1];
  const float* ln0_b  = (const float*)d_in[2];
  const float* ln1_g  = (const float*)d_in[3];
  const float* ln1_b  = (const float*)d_in[4];
  const float* ln2_g  = (const float*)d_in[5];
  const float* ln2_b  = (const float*)d_in[6];
  const float* amk    = (const float*)d_in[7];
  const float* amv    = (const float*)d_in[8];
  const float* amr    = (const float*)d_in[9];
  const float* adec   = (const float*)d_in[10];
  const float* afirst = (const float*)d_in[11];
  const float* aWk    = (const float*)d_in[12];
  const float* aWv    = (const float*)d_in[13];
  const float* aWr    = (const float*)d_in[14];
  const float* aWo    = (const float*)d_in[15];
  const float* akn_g  = (const float*)d_in[16];
  const float* akn_b  = (const float*)d_in[17];
  const float* fmk    = (const float*)d_in[18];
  const float* fmr    = (const float*)d_in[19];
  const float* fWk    = (const float*)d_in[20];
  const float* fWv    = (const float*)d_in[21];
  const float* fWr    = (const float*)d_in[22];
  const float* fkn_g  = (const float*)d_in[23];
  const float* fkn_b  = (const float*)d_in[24];

  int CB = 32;
  {
    const int cands[3] = {128, 64, 32};
    for (int i = 0; i < 3; ++i)
      if (make_layout(cands[i]).end <= ws_size) { CB = cands[i]; break; }
  }
  Layout L = make_layout(CB);
  int nchunk = 128 / CB;
  int M = CB * 196;
  size_t MC = (size_t)M * 768;

  uint8_t* ws = (uint8_t*)d_ws;
  bf16_t* WkT = (bf16_t*)(ws + L.wk);
  bf16_t* WvT = (bf16_t*)(ws + L.wv);
  bf16_t* WrT = (bf16_t*)(ws + L.wr);
  bf16_t* WoT = (bf16_t*)(ws + L.wo);
  bf16_t* FkT = (bf16_t*)(ws + L.fk);
  bf16_t* FvT = (bf16_t*)(ws + L.fv);
  bf16_t* FrT = (bf16_t*)(ws + L.fr);
  float*  ST  = (float*)(ws + L.st);
  uint8_t* big = ws + L.big;
  float*  K32 = (float*)(big);
  float*  V32 = (float*)(big + MC * 4);
  bf16_t* P16 = (bf16_t*)(big + MC * 8);
  bf16_t* Q16 = (bf16_t*)(big + MC * 10);
  bf16_t* R16 = (bf16_t*)(big + MC * 12);
  bf16_t* SR16 = (bf16_t*)(big + MC * 14);
  bf16_t* KFa = (bf16_t*)(big);            // M x 3072 bf16 (aliases K32..Q16, dead by then)
  bf16_t* KFb = (bf16_t*)(big + MC * 8);   // M x 3072 bf16
  bf16_t* A16 = (bf16_t*)(ws + L.a16);
  bf16_t* B16 = (bf16_t*)(ws + L.b16);
  bf16_t* C16 = (bf16_t*)(ws + L.c16);

  k_tcvt<<<dim3(24, 24), 256, 0, stream>>>(aWk, WkT, 768, 768);
  k_tcvt<<<dim3(24, 24), 256, 0, stream>>>(aWv, WvT, 768, 768);
  k_tcvt<<<dim3(24, 24), 256, 0, stream>>>(aWr, WrT, 768, 768);
  k_tcvt<<<dim3(24, 24), 256, 0, stream>>>(aWo, WoT, 768, 768);
  k_tcvt<<<dim3(96, 24), 256, 0, stream>>>(fWk, FkT, 768, 3072);
  k_tcvt<<<dim3(24, 96), 256, 0, stream>>>(fWv, FvT, 3072, 768);
  k_tcvt<<<dim3(24, 24), 256, 0, stream>>>(fWr, FrT, 768, 768);

  int rowb = M / 4;
  int Mt = M / 128;
  int wkvb = (CB * 768) / 256;

  for (int ch = 0; ch < nchunk; ++ch) {
    const float* xin = x + (size_t)ch * MC;
    float* XB = (float*)d_out + (size_t)ch * MC;   // residual stream lives in d_out

    // ---- attention half ----
    k_ln0<<<rowb, 256, 0, stream>>>(xin, ln0_g, ln0_b, XB, ST, M);
    k_mix<3><<<rowb, 256, 0, stream>>>(XB, ST, ln1_g, ln1_b, amk, amv, amr, A16, B16, C16, M);
    {
      GemmBatch gb{};
      gb.a[0] = {A16, WkT, K32, nullptr, nullptr, EPI_F32};
      gb.a[1] = {B16, WvT, V32, nullptr, nullptr, EPI_F32};
      gb.a[2] = {C16, WrT, SR16, nullptr, nullptr, EPI_SIG_BF16};
      k_gemm<<<dim3(6 * Mt, 1, 3), 256, 0, stream>>>(gb, M, 768, 768, Mt, 6);
    }
    k_wkv_bwd<<<wkvb, 256, 0, stream>>>(K32, V32, adec, P16, Q16, CB);
    k_wkv_fwd<<<wkvb, 256, 0, stream>>>(K32, V32, adec, afirst, P16, Q16, R16, CB);
    k_ln_mul<<<rowb, 256, 0, stream>>>(R16, SR16, akn_g, akn_b, A16, M);
    {
      GemmBatch gb{};
      gb.a[0] = {A16, WoT, XB, nullptr, nullptr, EPI_ADD};
      k_gemm<<<dim3(6 * Mt, 1, 1), 256, 0, stream>>>(gb, M, 768, 768, Mt, 6);
    }

    // ---- ffn half ----
    k_stats<<<rowb, 256, 0, stream>>>(XB, ST, M);
    k_mix<2><<<rowb, 256, 0, stream>>>(XB, ST, ln2_g, ln2_b, fmk, nullptr, fmr, A16, nullptr, C16, M);
    {
      GemmBatch gb{};
      gb.a[0] = {A16, FkT, KFa, nullptr, nullptr, EPI_RELU2_BF16};
      k_gemm<<<dim3(24 * Mt, 1, 1), 256, 0, stream>>>(gb, M, 3072, 768, Mt, 24);
    }
    {
      GemmBatch gb{};
      gb.a[0] = {C16, FrT, B16, nullptr, nullptr, EPI_SIG_BF16};
      k_gemm<<<dim3(6 * Mt, 1, 1), 256, 0, stream>>>(gb, M, 768, 768, Mt, 6);
    }
    k_ln_hid<<<rowb, 256, 0, stream>>>(KFa, fkn_g, fkn_b, KFb, M);
    {
      GemmBatch gb{};
      gb.a[0] = {KFb, FvT, XB, B16, XB, EPI_GATE};
      k_gemm<<<dim3(6 * Mt, 1, 1), 256, 0, stream>>>(gb, M, 768, 3072, Mt, 6);
    }
  }
}